// Round 5
// baseline (283.462 us; speedup 1.0000x reference)
//
#include <hip/hip_runtime.h>
#include <hip/hip_bf16.h>

#define NEMB  4096
#define DIM   128
#define NROWS 32768
#define MARGIN 3.5e-4f   // >= 3x worst-case approx error bound (see theory)

typedef _Float16 half8  __attribute__((ext_vector_type(8)));
typedef _Float16 half4v __attribute__((ext_vector_type(4)));
typedef _Float16 half2v __attribute__((ext_vector_type(2)));
typedef float    float4v __attribute__((ext_vector_type(4)));

typedef const __attribute__((address_space(1))) void* gas_ptr;
typedef __attribute__((address_space(3))) void*       las_ptr;

__device__ __forceinline__ void gload16(const void* g, void* l) {
    __builtin_amdgcn_global_load_lds((gas_ptr)g, (las_ptr)l, 16, 0, 0);
}

__device__ __forceinline__ half2v hmin2(half2v a, half2v b) {
    half2v r;
    r.x = (a.x < b.x) ? a.x : b.x;
    r.y = (a.y < b.y) ? a.y : b.y;
    return r;
}

// ---------------- K1: fused split-to-fp16 + numpy-pairwise row sum-of-squares ----------
// Covers x (rows 0..32767, scale 1) and W (rows 0..4095, scale 2^16).
// Pairwise sum replicates np.sum(a*a,axis=1) fp32 semantics exactly (8 strided
// accumulators + binary tree).
__launch_bounds__(256)
__global__ void k_prep(const float* __restrict__ x, const float* __restrict__ W,
                       _Float16* __restrict__ Xh, _Float16* __restrict__ Wh,
                       float* __restrict__ sxx, float* __restrict__ sww) {
    const int b = blockIdx.x;               // 4608 blocks, 8 rows each
    const int t = threadIdx.x;
    const bool isX = (b < NROWS / 8);
    const float* src   = isX ? x : W;
    _Float16*    dsth  = isX ? Xh : Wh;
    float*       dsts  = isX ? sxx : sww;
    const int    rbase = isX ? b * 8 : (b - NROWS / 8) * 8;
    const float  scale = isX ? 1.0f : 65536.0f;

    // phase A: convert 8 rows (256 float4s) to scaled fp16
    const size_t i4 = (size_t)rbase * 32 + t;
    const float4 v = ((const float4*)src)[i4];
    half4v hv = { (_Float16)(v.x * scale), (_Float16)(v.y * scale),
                  (_Float16)(v.z * scale), (_Float16)(v.w * scale) };
    *(half4v*)(dsth + i4 * 4) = hv;

    // phase B: wave 0 computes the 8 rows' pairwise sum of squares (L1/L2-hot)
    if (t < 64) {
        const int row = rbase + (t >> 3);
        const int j   = t & 7;
        const float* p = src + (size_t)row * DIM + j;
        float vv = p[0];
        float r = __fmul_rn(vv, vv);
        #pragma unroll
        for (int q = 1; q < 16; ++q) { vv = p[q * 8]; r = __fadd_rn(r, __fmul_rn(vv, vv)); }
        float o = __shfl_xor(r, 1, 64); r = __fadd_rn(r, o);
        o = __shfl_xor(r, 2, 64); r = __fadd_rn(r, o);
        o = __shfl_xor(r, 4, 64); r = __fadd_rn(r, o);
        if (j == 0) dsts[row] = r;
    }
}

// ---------------- K2: single-pass fp16 MFMA approx scores + per-16-code-group minima ----
// s~ = sww_c - acc*2^-15 (acc at scale 2^16). gmin[row][g] (fp16), g in [0,256),
// group g = codes [16g, 16g+16).
__launch_bounds__(256)
__global__ void k_score1(const _Float16* __restrict__ Xh, const _Float16* __restrict__ Wh,
                         const float* __restrict__ sww, _Float16* __restrict__ gmin) {
    __shared__ _Float16 sA[128 * 32], sB[128 * 32];
    __shared__ float ssw[128];

    const int tid  = threadIdx.x;
    const int wv   = tid >> 6;
    const int lane = tid & 63;
    const int l15  = lane & 15;
    const int quad = lane >> 4;
    const int r0   = blockIdx.x * 128;
    const int cb   = blockIdx.y * 128;

    if (tid < 128) ssw[tid] = sww[cb + tid];

    float4v acc[2][8];
    #pragma unroll
    for (int tm = 0; tm < 2; ++tm)
        #pragma unroll
        for (int tn = 0; tn < 8; ++tn) acc[tm][tn] = (float4v){0.f, 0.f, 0.f, 0.f};

    const int gr = lane >> 2;
    const int gk = (lane & 3) * 8;

    for (int c = 0; c < 4; ++c) {
        const int k0 = c * 32;
        __syncthreads();
        #pragma unroll
        for (int rep = 0; rep < 2; ++rep) {
            const int j16 = (wv + rep * 4) * 16;
            const size_t goff = (size_t)(j16 + gr) * DIM + k0 + gk;
            gload16(Xh + (size_t)r0 * DIM + goff, &sA[j16 * 32]);
            gload16(Wh + (size_t)cb * DIM + goff, &sB[j16 * 32]);
        }
        __syncthreads();

        const int m0 = wv * 32;
        const half8 a0 = *(const half8*)&sA[(m0 + l15) * 32 + quad * 8];
        const half8 a1 = *(const half8*)&sA[(m0 + 16 + l15) * 32 + quad * 8];
        #pragma unroll
        for (int tn = 0; tn < 8; ++tn) {
            const half8 b = *(const half8*)&sB[(tn * 16 + l15) * 32 + quad * 8];
            acc[0][tn] = __builtin_amdgcn_mfma_f32_16x16x32_f16(a0, b, acc[0][tn], 0, 0, 0);
            acc[1][tn] = __builtin_amdgcn_mfma_f32_16x16x32_f16(a1, b, acc[1][tn], 0, 0, 0);
        }
    }

    // epilogue: per (row, tn) min over the 16 cols (l15 lanes), 2 tn packed as fp16x2
    #pragma unroll
    for (int tm = 0; tm < 2; ++tm) {
        #pragma unroll
        for (int r = 0; r < 4; ++r) {
            const int rl = wv * 32 + tm * 16 + quad * 4 + r;
            #pragma unroll
            for (int tp = 0; tp < 4; ++tp) {   // tn pair
                const float s0 = ssw[(tp * 2 + 0) * 16 + l15] - acc[tm][tp * 2 + 0][r] * 0x1p-15f;
                const float s1 = ssw[(tp * 2 + 1) * 16 + l15] - acc[tm][tp * 2 + 1][r] * 0x1p-15f;
                union { half2v h; unsigned u; } cur, oth;
                cur.h.x = (_Float16)s0; cur.h.y = (_Float16)s1;
                #pragma unroll
                for (int off = 1; off < 16; off <<= 1) {
                    oth.u = __shfl_xor((int)cur.u, off, 64);
                    cur.h = hmin2(cur.h, oth.h);
                }
                if (l15 == 0)
                    *(half2v*)&gmin[(size_t)(r0 + rl) * 256 + blockIdx.y * 8 + tp * 2] = cur.h;
            }
        }
    }
}

// ---------------- K3: per-row global min + margin flags (256-bit mask) ----------------
// lane l holds groups 4l..4l+3; ballot j gives flag bits for groups {4l+j}.
__launch_bounds__(256)
__global__ void k_flag(const _Float16* __restrict__ gmin, unsigned long long* __restrict__ flags) {
    const int row  = blockIdx.x * 4 + (threadIdx.x >> 6);
    const int lane = threadIdx.x & 63;
    const half4v g4 = *(const half4v*)&gmin[(size_t)row * 256 + lane * 4];
    float v0 = (float)g4.x, v1 = (float)g4.y, v2 = (float)g4.z, v3 = (float)g4.w;
    float m = fminf(fminf(v0, v1), fminf(v2, v3));
    #pragma unroll
    for (int off = 1; off < 64; off <<= 1) m = fminf(m, __shfl_xor(m, off, 64));
    const float thr = m + MARGIN;
    const unsigned long long b0 = __ballot(v0 <= thr);
    const unsigned long long b1 = __ballot(v1 <= thr);
    const unsigned long long b2 = __ballot(v2 <= thr);
    const unsigned long long b3 = __ballot(v3 <= thr);
    if (lane == 0) {
        unsigned long long* fp = flags + (size_t)row * 4;
        fp[0] = b0; fp[1] = b1; fp[2] = b2; fp[3] = b3;
    }
}

// ---------------- K4: exact refine (numpy fp32 semantics) + gather + loss partial ------
// One wave per row. For each flagged group: 16 codes x 4 k-parts across 64 lanes;
// exact d = fl(fl(sxx+sww) - fl(2*dot)); global min with lowest-index ties.
__launch_bounds__(256)
__global__ void k_refine(const float* __restrict__ x, const float* __restrict__ W,
                         const float* __restrict__ sxx, const float* __restrict__ sww,
                         const unsigned long long* __restrict__ flags,
                         float* __restrict__ out0, float* __restrict__ out1,
                         float* __restrict__ out_idx, float* __restrict__ part) {
    const int row  = blockIdx.x * 4 + (threadIdx.x >> 6);
    const int lane = threadIdx.x & 63;
    const int cig  = lane >> 2;     // code within group
    const int kp   = lane & 3;      // k quarter
    const float sxr = sxx[row];
    const float* xr = x + (size_t)row * DIM;
    const float* xp = xr + kp * 32;

    float bv = 3.0e38f;
    int   bi = 0x7fffffff;

    const unsigned long long* fp = flags + (size_t)row * 4;
    #pragma unroll
    for (int j = 0; j < 4; ++j) {
        unsigned long long msk = fp[j];
        while (msk) {
            const int l = __builtin_ctzll(msk);
            msk &= msk - 1;
            const int g = l * 4 + j;
            const int c = g * 16 + cig;
            const float* wr = W + (size_t)c * DIM + kp * 32;
            float dot = 0.f;
            #pragma unroll
            for (int k = 0; k < 32; ++k) dot = fmaf(xp[k], wr[k], dot);
            float o = __shfl_xor(dot, 1, 64); dot = __fadd_rn(dot, o);
            o = __shfl_xor(dot, 2, 64); dot = __fadd_rn(dot, o);   // (p0+p1)+(p2+p3)
            const float A = __fadd_rn(sxr, sww[c]);
            const float d = __fsub_rn(A, __fmul_rn(2.0f, dot));
            if (d < bv || (d == bv && c < bi)) { bv = d; bi = c; }
        }
    }
    #pragma unroll
    for (int off = 1; off < 64; off <<= 1) {
        const float ov = __shfl_xor(bv, off, 64);
        const int   oi = __shfl_xor(bi, off, 64);
        if (ov < bv || (ov == bv && oi < bi)) { bv = ov; bi = oi; }
    }

    // gather winner row + outputs + loss partial
    const float2 wv2 = *(const float2*)(W + (size_t)bi * DIM + lane * 2);
    const float2 xv2 = *(const float2*)(xr + lane * 2);
    const float d0 = wv2.x - xv2.x, d1 = wv2.y - xv2.y;
    float p = fmaf(d0, d0, d1 * d1);
    *(float2*)(out0 + (size_t)row * DIM + lane * 2) = wv2;
    *(float2*)(out1 + (size_t)row * DIM + lane * 2) = wv2;
    #pragma unroll
    for (int off = 32; off > 0; off >>= 1) p += __shfl_down(p, off, 64);
    if (lane == 0) {
        part[row] = p;
        out_idx[row] = (float)bi;
    }
}

// ---------------- K5: reduce 32768 partials -> loss ----------------
__global__ void k_lsum(const float* __restrict__ part, float* __restrict__ out_loss) {
    __shared__ float red[256];
    const int tid = threadIdx.x;
    float s = 0.f;
    const float4* p4 = (const float4*)part;
    for (int i = tid; i < NROWS / 4; i += 256) {
        const float4 v = p4[i];
        s += (v.x + v.y) + (v.z + v.w);
    }
    red[tid] = s;
    __syncthreads();
    #pragma unroll
    for (int w = 128; w > 0; w >>= 1) {
        if (tid < w) red[tid] += red[tid + w];
        __syncthreads();
    }
    if (tid == 0) out_loss[0] = red[0] * 1.25f / (float)(NROWS * DIM);
}

extern "C" void kernel_launch(void* const* d_in, const int* in_sizes, int n_in,
                              void* d_out, int out_size, void* d_ws, size_t ws_size,
                              hipStream_t stream) {
    const float* x = (const float*)d_in[0];   // [32768,128]
    const float* W = (const float*)d_in[1];   // [4096,128]
    float* out = (float*)d_out;

    float* out_q2d  = out;
    float* out_qst  = out + (size_t)NROWS * DIM;
    float* out_loss = out + (size_t)2 * NROWS * DIM;
    float* out_idx  = out + (size_t)2 * NROWS * DIM + 1;

    // ws layout (float slots), total ~27.5 MB
    float* ws   = (float*)d_ws;
    float* sww  = ws;                                   // 4096
    float* sxx  = ws + 4096;                            // 32768
    float* part = ws + 4096 + 32768;                    // 32768
    unsigned long long* flags = (unsigned long long*)(ws + 4096 + 2 * 32768); // 32768*4 u64 = 1 MB
    _Float16* gmin = (_Float16*)(ws + 4096 + 2 * 32768 + 65536);  // 32768*256 f16 = 16.8 MB
    _Float16* Xh = gmin + (size_t)NROWS * 256;          // 32768*128 f16
    _Float16* Wh = Xh + (size_t)NROWS * DIM;            // 4096*128 f16

    k_prep<<<(NROWS + NEMB) / 8, 256, 0, stream>>>(x, W, Xh, Wh, sxx, sww);
    dim3 g2(NROWS / 128, NEMB / 128);
    k_score1<<<g2, 256, 0, stream>>>(Xh, Wh, sww, gmin);
    k_flag<<<NROWS / 4, 256, 0, stream>>>(gmin, flags);
    k_refine<<<NROWS / 4, 256, 0, stream>>>(x, W, sxx, sww, flags,
                                            out_q2d, out_qst, out_idx, part);
    k_lsum<<<1, 256, 0, stream>>>(part, out_loss);
}